// Round 6
// baseline (573.212 us; speedup 1.0000x reference)
//
#include <hip/hip_runtime.h>
#include <hip/hip_bf16.h>

#define D_MODEL 4096
#define D_FF    16384
#define SEQ     1024

typedef __attribute__((ext_vector_type(4))) float          fvec4;
typedef __attribute__((ext_vector_type(4))) float          f32x4;
typedef __attribute__((ext_vector_type(4))) int            i32x4;
typedef __attribute__((ext_vector_type(8))) short          bf16x8;
typedef __attribute__((ext_vector_type(4))) unsigned short u16x4;

constexpr int BM = 256, BN = 256, BK = 64;
constexpr int NTHREADS = 512;            // 8 waves: 2 (M) x 4 (N)
constexpr int NT = D_MODEL / BK;         // 64 K-steps
constexpr size_t WS_A_BYTES = 4ull * NT * 32768;  // 8 MiB pre-swizzled A images

// fp32 -> bf16 RNE. Exact for small ints.
__device__ __forceinline__ unsigned short f2bf(float f) {
    unsigned int u = __builtin_bit_cast(unsigned int, f);
    u += 0x7FFFu + ((u >> 16) & 1u);
    return (unsigned short)(u >> 16);
}

// Dtype-agnostic bf16 of one kernel word (safe path). Exact either way.
__device__ __forceinline__ unsigned short kq_bf16(unsigned int w) {
    int iv = (int)w;
    float fi = (float)iv;
    unsigned int fw = ((unsigned int)(iv + 8) <= 15u)
                        ? __builtin_bit_cast(unsigned int, fi) : w;
    return (unsigned short)(fw >> 16);
}

// ---- pre-kernel: X fp32 -> bf16 once, stored as pre-swizzled A-tile images ----
// Image byte layout == main kernel's LDS A layout -> main-kernel A staging is
// a pure linear copy (global_load_lds-able).
__global__ __launch_bounds__(256)
void preconv_A(const float* __restrict__ X, unsigned short* __restrict__ wsA)
{
    size_t u = (size_t)blockIdx.x * 256 + threadIdx.x;  // one 8B unit (4 bf16)
    size_t g = u * 8;
    int bm    = (int)(g >> 21);          // 2 MiB per bm group
    int r1    = (int)(g & 2097151);
    int kt    = r1 >> 15;                // 32 KiB per K-tile
    int b     = r1 & 32767;
    int m     = b >> 7;                  // row within tile (128 B per row)
    int pslot = (b >> 4) & 7;            // physical 16B slot
    int t     = pslot ^ (m & 7);         // logical k16 slot (inverse XOR swizzle)
    int o     = (b >> 3) & 1;
    int k     = t * 8 + o * 4;
    const fvec4 v = *reinterpret_cast<const fvec4*>(
        &X[(size_t)(bm * 256 + m) * D_MODEL + kt * BK + k]);
    u16x4 h;
    #pragma unroll
    for (int e = 0; e < 4; ++e) h[e] = f2bf(v[e]);
    *reinterpret_cast<u16x4*>((char*)wsA + g) = h;
}

template <bool PRE>
__global__ __launch_bounds__(NTHREADS, 2)
void int4_gemm_kernel(const float* __restrict__ X, const unsigned int* __restrict__ Kq,
                      const float* __restrict__ scale, float* __restrict__ out,
                      const unsigned short* __restrict__ wsA)
{
    __shared__ short A_lds[2][BM * BK];
    __shared__ short B_lds[2][BN * BK];

    const int bid = blockIdx.x;
    const int bm  = (bid >> 3) & 3;             // 4 M-blocks share one B panel
    const int bn  = (bid & 7) * 8 + (bid >> 5); // XCD-grouped, bijective

    const int tid  = threadIdx.x;
    const int lane = tid & 63;
    const int w    = tid >> 6;
    const int wr   = w >> 2;
    const int wc   = w & 3;
    const int lrow = lane & 15;
    const int lgrp = lane >> 4;

    const int row0 = bm * BM;
    const int col0 = bn * BN;

    const int b_n  = tid & 255;   // B staging: column owned by this thread
    const int b_k8 = tid >> 8;    // k-octet base

    // ---- one-time dtype detect (wave-uniform; all waves sample Kq[0..63]) ----
    // fp32-encoded nonzero int4 values are never in {-8..7} as int32.
    unsigned int sw = Kq[lane];
    int siv = (int)sw;
    const bool is_f32 = __any((sw != 0u) && !((unsigned int)(siv + 8) <= 15u));

    f32x4 acc[8][4];
    #pragma unroll
    for (int i = 0; i < 8; ++i)
        #pragma unroll
        for (int j = 0; j < 4; ++j)
            acc[i][j] = (f32x4){0.f, 0.f, 0.f, 0.f};

    unsigned int bReg[4][8];   // in-flight B tile (raw words)

    auto issueB = [&](int kt) {
        const int kbase = kt * BK;
        #pragma unroll
        for (int i = 0; i < 4; ++i) {
            int k8 = b_k8 + i * 2;
            const unsigned int* src = &Kq[(size_t)(kbase + k8 * 8) * D_FF + col0 + b_n];
            #pragma unroll
            for (int j = 0; j < 8; ++j) bReg[i][j] = src[(size_t)j * D_FF];
        }
    };
    auto convertB = [&](short* Bbuf) {
        char* bB = (char*)Bbuf;
        if (is_f32) {
            // provably fp32 bit patterns: bf16 = top 16 bits, exact
            #pragma unroll
            for (int i = 0; i < 4; ++i) {
                int k8 = b_k8 + i * 2;
                i32x4 d;
                #pragma unroll
                for (int p = 0; p < 4; ++p)
                    d[p] = (int)((bReg[i][2 * p] >> 16) |
                                 (bReg[i][2 * p + 1] & 0xFFFF0000u));
                int boff = b_n * 128 + ((k8 ^ (b_n & 7)) * 16);
                *reinterpret_cast<i32x4*>(bB + boff) = d;
            }
        } else {
            #pragma unroll
            for (int i = 0; i < 4; ++i) {
                int k8 = b_k8 + i * 2;
                bf16x8 h;
                #pragma unroll
                for (int j = 0; j < 8; ++j) h[j] = (short)kq_bf16(bReg[i][j]);
                int boff = b_n * 128 + ((k8 ^ (b_n & 7)) * 16);
                *reinterpret_cast<bf16x8*>(bB + boff) = h;
            }
        }
    };
    // A stage via global_load_lds: ws image bytes == LDS bytes (linear copy).
    auto gllA = [&](int kt, int bufIdx) {
        const char* src = (const char*)wsA + ((size_t)bm << 21) + ((size_t)kt << 15);
        char* dst = (char*)A_lds[bufIdx];
        #pragma unroll
        for (int i = 0; i < 4; ++i) {
            int off = i * 8192 + tid * 16;
            __builtin_amdgcn_global_load_lds(
                (__attribute__((address_space(1))) void*)(void*)(src + off),
                (__attribute__((address_space(3))) void*)(dst + off),
                16, 0, 0);
        }
    };
    auto stageA_conv = [&](int kt, short* Abuf) {  // fallback (!PRE)
        const int a_m = tid >> 4, a_f4 = tid & 15;
        const int kbase = kt * BK;
        char* aB = (char*)Abuf;
        #pragma unroll
        for (int i = 0; i < 8; ++i) {
            int m = a_m + i * 32;
            const fvec4 v = *reinterpret_cast<const fvec4*>(
                &X[(size_t)(row0 + m) * D_MODEL + kbase + a_f4 * 4]);
            u16x4 h;
            #pragma unroll
            for (int e = 0; e < 4; ++e) h[e] = f2bf(v[e]);
            int boff = m * 128 + (((a_f4 >> 1) ^ (m & 7)) * 16) + (a_f4 & 1) * 8;
            *reinterpret_cast<u16x4*>(aB + boff) = h;
        }
    };
    auto mfma_step = [&](const short* Abuf, const short* Bbuf) {
        const char* aB = (const char*)Abuf;
        const char* bB = (const char*)Bbuf;
        #pragma unroll
        for (int ks = 0; ks < 2; ++ks) {
            bf16x8 afrag[8];
            bf16x8 bfrag[4];
            #pragma unroll
            for (int i = 0; i < 8; ++i) {
                int r = wr * 128 + i * 16 + lrow;
                int s = (ks * 4 + lgrp) ^ (r & 7);
                afrag[i] = *reinterpret_cast<const bf16x8*>(aB + r * 128 + s * 16);
            }
            #pragma unroll
            for (int j = 0; j < 4; ++j) {
                int n = wc * 64 + j * 16 + lrow;
                int s = (ks * 4 + lgrp) ^ (n & 7);
                bfrag[j] = *reinterpret_cast<const bf16x8*>(bB + n * 128 + s * 16);
            }
            __builtin_amdgcn_s_setprio(1);
            #pragma unroll
            for (int i = 0; i < 8; ++i)
                #pragma unroll
                for (int j = 0; j < 4; ++j)
                    acc[i][j] = __builtin_amdgcn_mfma_f32_16x16x32_bf16(
                        afrag[i], bfrag[j], acc[i][j], 0, 0, 0);
            __builtin_amdgcn_s_setprio(0);
        }
    };

    if constexpr (PRE) {
        // T4 barrier: gll(A) counted-retired (issued before the 32 B loads),
        // B loads stay in flight across the barrier. Never vmcnt(0) mid-loop.
        #define BAR_VM32() do { \
            asm volatile("s_waitcnt vmcnt(32) lgkmcnt(0)" ::: "memory"); \
            __builtin_amdgcn_s_barrier(); } while (0)
        #define BAR_VM0() do { \
            asm volatile("s_waitcnt vmcnt(0) lgkmcnt(0)" ::: "memory"); \
            __builtin_amdgcn_s_barrier(); } while (0)

        // Prologue: tile 0 -> buf0; loads(1) in flight.
        issueB(0);
        gllA(0, 0);
        convertB(B_lds[0]);   // reg-dep waits B(0); gll(0) retires under it
        issueB(1);
        BAR_VM32();

        // Invariant at loop head (kt even): buf0 holds tile kt; bReg = loads(kt+1)
        // in flight. Body: stage kt+1 -> buf^1, issue kt+2, compute kt.
        for (int kt = 0; kt < NT - 2; kt += 2) {
            convertB(B_lds[1]);          // consumes bReg(kt+1)
            gllA(kt + 1, 1);             // 4 gll issued BEFORE next 32 B loads
            issueB(kt + 2);
            mfma_step(A_lds[0], B_lds[0]);
            BAR_VM32();

            convertB(B_lds[0]);          // consumes bReg(kt+2)
            gllA(kt + 2, 0);
            issueB(kt + 3);
            mfma_step(A_lds[1], B_lds[1]);
            BAR_VM32();
        }
        // Peeled tail: tiles NT-2, NT-1 (no further issues -> counted wait
        // would be wrong; drain fully instead).
        convertB(B_lds[1]);              // tile NT-1 (loads issued last body)
        gllA(NT - 1, 1);
        mfma_step(A_lds[0], B_lds[0]);   // tile NT-2
        BAR_VM0();
        mfma_step(A_lds[1], B_lds[1]);   // tile NT-1
        #undef BAR_VM32
        #undef BAR_VM0
    } else {
        // Fallback (no ws): round-4 structure, lgkm-only barrier (no gll used).
        auto bar = [&]() {
            asm volatile("s_waitcnt lgkmcnt(0)" ::: "memory");
            __builtin_amdgcn_s_barrier();
        };
        issueB(0);
        stageA_conv(0, A_lds[0]);
        convertB(B_lds[0]);
        issueB(1);
        bar();
        for (int kt = 0; kt < NT; kt += 2) {
            if (kt + 1 < NT) { convertB(B_lds[1]); stageA_conv(kt + 1, A_lds[1]); }
            if (kt + 2 < NT) issueB(kt + 2);
            mfma_step(A_lds[0], B_lds[0]);
            bar();
            if (kt + 2 < NT) { convertB(B_lds[0]); stageA_conv(kt + 2, A_lds[0]); }
            if (kt + 3 < NT) issueB(kt + 3);
            mfma_step(A_lds[1], B_lds[1]);
            bar();
        }
    }

    // ---- epilogue: per-column 1/scale, store fp32 ----
    // C/D layout (m89-verified): col = lane&15, row = (lane>>4)*4 + reg.
    #pragma unroll
    for (int j = 0; j < 4; ++j) {
        int col = col0 + wc * 64 + j * 16 + lrow;
        float rs = 1.0f / scale[col];
        #pragma unroll
        for (int i = 0; i < 8; ++i) {
            int r0 = row0 + wr * 128 + i * 16 + lgrp * 4;
            #pragma unroll
            for (int r = 0; r < 4; ++r)
                out[(size_t)(r0 + r) * D_FF + col] = acc[i][j][r] * rs;
        }
    }
}

extern "C" void kernel_launch(void* const* d_in, const int* in_sizes, int n_in,
                              void* d_out, int out_size, void* d_ws, size_t ws_size,
                              hipStream_t stream) {
    const float*        X     = (const float*)d_in[0];
    const unsigned int* Kq    = (const unsigned int*)d_in[1];
    const float*        scale = (const float*)d_in[2];
    float*              out   = (float*)d_out;

    dim3 grid((SEQ / BM) * (D_FF / BN));  // 256 blocks = 1/CU
    dim3 block(NTHREADS);

    if (ws_size >= WS_A_BYTES) {
        unsigned short* wsA = (unsigned short*)d_ws;
        preconv_A<<<dim3((unsigned)(WS_A_BYTES / 8 / 256)), dim3(256), 0, stream>>>(X, wsA);
        int4_gemm_kernel<true><<<grid, block, 0, stream>>>(X, Kq, scale, out, wsA);
    } else {
        int4_gemm_kernel<false><<<grid, block, 0, stream>>>(X, Kq, scale, out, nullptr);
    }
}